// Round 1
// 425.594 us; speedup vs baseline: 1.0688x; 1.0688x over previous
//
#include <hip/hip_runtime.h>
#include <stdint.h>

typedef unsigned short u16;
typedef unsigned int u32;
typedef __bf16 bf16x8 __attribute__((ext_vector_type(8)));
typedef float f32x4 __attribute__((ext_vector_type(4)));

#define SEQ 2048
#define BZ 16
#define DIM 1024

__device__ __forceinline__ u16 f2bf(float f) {
    union { float f; u32 u; } a; a.f = f;
    u32 r = a.u + 0x7FFFu + ((a.u >> 16) & 1u);   // RNE
    return (u16)(r >> 16);
}
__device__ __forceinline__ float bf2f(u16 u) {
    union { u32 u; float f; } a; a.u = ((u32)u) << 16;
    return a.f;
}
__device__ __forceinline__ void async16(const u16* g, u16* l) {
    __builtin_amdgcn_global_load_lds(
        (const __attribute__((address_space(1))) void*)g,
        (__attribute__((address_space(3))) void*)l, 16, 0, 0);
}

// ---------------------------------------------------------------------------
// K0a: xb[b][s][d] = bf16(x[s][b][d])   (transpose s<->b, convert)
// ---------------------------------------------------------------------------
__global__ void convert_x(const float* __restrict__ x, u16* __restrict__ xb)
{
    int s = blockIdx.x;
    int t = threadIdx.x;
    const float4* src = (const float4*)(x + (size_t)s * BZ * DIM);
    #pragma unroll
    for (int j = 0; j < 16; j++) {
        int idx = j * 256 + t;              // float4 index in [0, 4096)
        float4 v = src[idx];
        int e = idx * 4;
        int b = e >> 10, d = e & 1023;
        u32 lo = f2bf(v.x) | ((u32)f2bf(v.y) << 16);
        u32 hi = f2bf(v.z) | ((u32)f2bf(v.w) << 16);
        *(uint2*)(xb + ((size_t)b * SEQ + s) * DIM + d) = make_uint2(lo, hi);
    }
}

// ---------------------------------------------------------------------------
// K0: transpose+convert.  z<16: Wbt[z][f][e] = W[id_z][e][f]   (bf16)
//     z==16:              Wt[d][e]   = W_base[e][d]            (bf16)
// ---------------------------------------------------------------------------
__global__ void transpose_cvt(const float* __restrict__ W,
                              const float* __restrict__ W_base,
                              const int* __restrict__ lang_ids,
                              const int* __restrict__ dict_len,
                              u16* __restrict__ Wt,
                              u16* __restrict__ Wbt)
{
    int z = blockIdx.z;
    const float* S;
    u16* D;
    if (z < BZ) {
        int id = dict_len[0] - 1 - lang_ids[z];
        S = W + (size_t)id * DIM * DIM;
        D = Wbt + (size_t)z * DIM * DIM;
    } else {
        S = W_base;
        D = Wt;
    }
    __shared__ float tile[32][33];
    int tx = threadIdx.x, ty = threadIdx.y;       // 32 x 8
    int x0 = blockIdx.x * 32, y0 = blockIdx.y * 32;
    #pragma unroll
    for (int i = 0; i < 4; i++)
        tile[ty + 8 * i][tx] = S[(size_t)(y0 + ty + 8 * i) * DIM + x0 + tx];
    __syncthreads();
    #pragma unroll
    for (int i = 0; i < 4; i++)
        D[(size_t)(x0 + ty + 8 * i) * DIM + y0 + tx] = f2bf(tile[tx][ty + 8 * i]);
}

// ---------------------------------------------------------------------------
// K1: bb[b][f] = sum_e b_base[e] * Wbt[b][f][e]  + bias[id_b][f]
// ---------------------------------------------------------------------------
__global__ void bb_kernel(const u16* __restrict__ Wbt,
                          const float* __restrict__ b_base,
                          const float* __restrict__ bias,
                          const int* __restrict__ lang_ids,
                          const int* __restrict__ dict_len,
                          float* __restrict__ bb)
{
    int gw = blockIdx.x * 4 + (threadIdx.x >> 6);
    int b = gw >> 10;
    int f = gw & 1023;
    int lane = threadIdx.x & 63;
    const u16* row = Wbt + ((size_t)b * DIM + f) * DIM;
    float s = 0.f;
    #pragma unroll
    for (int i = 0; i < DIM / 64; i++)
        s += bf2f(row[lane + 64 * i]) * b_base[lane + 64 * i];
    #pragma unroll
    for (int off = 32; off; off >>= 1)
        s += __shfl_xor(s, off, 64);
    if (lane == 0) {
        int id = dict_len[0] - 1 - lang_ids[b];
        bb[b * DIM + f] = s + bias[(size_t)id * DIM + f];
    }
}

// ---------------------------------------------------------------------------
// K2: CT[b][f][d] = sum_e Wbt[b][f][e] * Wt[d][e]   (bf16 out)
// 128x128 tile, BK=32, double-buffered global_load_lds, XCD-swizzled 1D grid
// grid = 1024 blocks: per XCD 128 contiguous virt = 2 whole batches
// ---------------------------------------------------------------------------
__global__ void gemm1_kernel(const u16* __restrict__ Wbt,
                             const u16* __restrict__ Wt,
                             u16* __restrict__ CT)
{
    int bid = blockIdx.x;
    int virt = ((bid & 7) << 7) + (bid >> 3);     // bijective, 1024 % 8 == 0
    int b    = virt >> 6;                         // 64 blocks per batch
    int rem  = virt & 63;
    int f0   = (rem >> 3) << 7;
    int d0   = (rem & 7) << 7;

    const u16* A = Wbt + (size_t)b * DIM * DIM;   // [f][e]
    const u16* B = Wt;                            // [d][e]
    u16* C = CT + (size_t)b * DIM * DIM;          // [f][d]

    __shared__ u16 As[2 * 128 * 32];
    __shared__ u16 Bs[2 * 128 * 32];

    int tid = threadIdx.x;
    int wave = tid >> 6, lane = tid & 63;
    int wm = (wave >> 1) * 64, wn = (wave & 1) * 64;
    int quad = lane >> 4, lr = lane & 15;

    int srow = wave * 32 + (lane >> 2);
    int scol = (lane & 3) * 8;
    const u16* ga0 = A + (size_t)(f0 + srow) * DIM + scol;
    const u16* ga1 = ga0 + (size_t)16 * DIM;
    const u16* gb0 = B + (size_t)(d0 + srow) * DIM + scol;
    const u16* gb1 = gb0 + (size_t)16 * DIM;
    int lofs = wave * 32 * 32;                    // wave-uniform LDS base

    f32x4 acc[4][4];
    #pragma unroll
    for (int i = 0; i < 4; i++)
        #pragma unroll
        for (int j = 0; j < 4; j++)
            #pragma unroll
            for (int e = 0; e < 4; e++) acc[i][j][e] = 0.f;

    // prologue: stage tile 0 into buffer 0
    async16(ga0, As + lofs); async16(ga1, As + lofs + 16 * 32);
    async16(gb0, Bs + lofs); async16(gb1, Bs + lofs + 16 * 32);
    ga0 += 32; ga1 += 32; gb0 += 32; gb1 += 32;
    __syncthreads();

    int cur = 0;
    for (int k0 = 0; k0 < DIM; k0 += 32) {
        int nxt = cur ^ 1;
        if (k0 + 32 < DIM) {                      // stage next tile (overlaps compute)
            u16* da = As + nxt * 4096 + lofs;
            u16* db = Bs + nxt * 4096 + lofs;
            async16(ga0, da); async16(ga1, da + 16 * 32);
            async16(gb0, db); async16(gb1, db + 16 * 32);
            ga0 += 32; ga1 += 32; gb0 += 32; gb1 += 32;
        }
        const u16* ra = As + cur * 4096;
        const u16* rb = Bs + cur * 4096;
        bf16x8 af[4], bfv[4];
        #pragma unroll
        for (int mt = 0; mt < 4; mt++)
            af[mt] = *(const bf16x8*)&ra[(wm + mt * 16 + lr) * 32 + quad * 8];
        #pragma unroll
        for (int nt = 0; nt < 4; nt++)
            bfv[nt] = *(const bf16x8*)&rb[(wn + nt * 16 + lr) * 32 + quad * 8];
        #pragma unroll
        for (int mt = 0; mt < 4; mt++)
            #pragma unroll
            for (int nt = 0; nt < 4; nt++)
                acc[mt][nt] = __builtin_amdgcn_mfma_f32_16x16x32_bf16(
                    af[mt], bfv[nt], acc[mt][nt], 0, 0, 0);
        __syncthreads();                          // drains vmcnt(0): next buffer ready
        cur = nxt;
    }
    #pragma unroll
    for (int mt = 0; mt < 4; mt++) {
        int fr = f0 + wm + mt * 16 + quad * 4;
        #pragma unroll
        for (int nt = 0; nt < 4; nt++) {
            int dc = d0 + wn + nt * 16 + lr;
            #pragma unroll
            for (int rr = 0; rr < 4; rr++)
                C[(size_t)(fr + rr) * DIM + dc] = f2bf(acc[mt][nt][rr]);
        }
    }
}

// ---------------------------------------------------------------------------
// K3: out[s][b][f] = sum_d xb[b][s][d] * CT[b][f][d] + bb[b][f]
// same dbuf structure; grid = 2048 blocks, per XCD 256 contiguous virt = 2 batches
// ---------------------------------------------------------------------------
__global__ void gemm2_kernel(const u16* __restrict__ xb,
                             const u16* __restrict__ CT,
                             const float* __restrict__ bb,
                             float* __restrict__ out)
{
    int bid = blockIdx.x;
    int virt = ((bid & 7) << 8) + (bid >> 3);     // bijective, 2048 % 8 == 0
    int b    = virt >> 7;                         // 128 blocks per batch
    int rem  = virt & 127;
    int s0   = (rem >> 3) << 7;                   // 16 s-tiles
    int f0   = (rem & 7) << 7;                    // 8 f-tiles

    const u16* A  = xb + (size_t)b * SEQ * DIM;   // [s][d]
    const u16* Bm = CT + (size_t)b * DIM * DIM;   // [f][d]

    __shared__ u16 As[2 * 128 * 32];
    __shared__ u16 Bs[2 * 128 * 32];

    int tid = threadIdx.x;
    int wave = tid >> 6, lane = tid & 63;
    int wm = (wave >> 1) * 64, wn = (wave & 1) * 64;
    int quad = lane >> 4, lr = lane & 15;

    int srow = wave * 32 + (lane >> 2);
    int scol = (lane & 3) * 8;
    const u16* ga0 = A + (size_t)(s0 + srow) * DIM + scol;
    const u16* ga1 = ga0 + (size_t)16 * DIM;
    const u16* gb0 = Bm + (size_t)(f0 + srow) * DIM + scol;
    const u16* gb1 = gb0 + (size_t)16 * DIM;
    int lofs = wave * 32 * 32;                    // wave-uniform LDS base

    f32x4 acc[4][4];
    #pragma unroll
    for (int i = 0; i < 4; i++)
        #pragma unroll
        for (int j = 0; j < 4; j++)
            #pragma unroll
            for (int e = 0; e < 4; e++) acc[i][j][e] = 0.f;

    // prologue: stage tile 0 into buffer 0
    async16(ga0, As + lofs); async16(ga1, As + lofs + 16 * 32);
    async16(gb0, Bs + lofs); async16(gb1, Bs + lofs + 16 * 32);
    ga0 += 32; ga1 += 32; gb0 += 32; gb1 += 32;
    __syncthreads();

    int cur = 0;
    for (int k0 = 0; k0 < DIM; k0 += 32) {
        int nxt = cur ^ 1;
        if (k0 + 32 < DIM) {                      // stage next tile (overlaps compute)
            u16* da = As + nxt * 4096 + lofs;
            u16* db = Bs + nxt * 4096 + lofs;
            async16(ga0, da); async16(ga1, da + 16 * 32);
            async16(gb0, db); async16(gb1, db + 16 * 32);
            ga0 += 32; ga1 += 32; gb0 += 32; gb1 += 32;
        }
        const u16* ra = As + cur * 4096;
        const u16* rb = Bs + cur * 4096;
        bf16x8 af[4], bfv[4];
        #pragma unroll
        for (int mt = 0; mt < 4; mt++)
            af[mt] = *(const bf16x8*)&ra[(wm + mt * 16 + lr) * 32 + quad * 8];
        #pragma unroll
        for (int nt = 0; nt < 4; nt++)
            bfv[nt] = *(const bf16x8*)&rb[(wn + nt * 16 + lr) * 32 + quad * 8];
        #pragma unroll
        for (int mt = 0; mt < 4; mt++)
            #pragma unroll
            for (int nt = 0; nt < 4; nt++)
                acc[mt][nt] = __builtin_amdgcn_mfma_f32_16x16x32_bf16(
                    af[mt], bfv[nt], acc[mt][nt], 0, 0, 0);
        __syncthreads();                          // drains vmcnt(0): next buffer ready
        cur = nxt;
    }
    #pragma unroll
    for (int nt = 0; nt < 4; nt++) {
        int fcol = f0 + wn + nt * 16 + lr;
        float bv = bb[b * DIM + fcol];
        #pragma unroll
        for (int mt = 0; mt < 4; mt++) {
            int sr = s0 + wm + mt * 16 + quad * 4;
            #pragma unroll
            for (int rr = 0; rr < 4; rr++)
                out[((size_t)(sr + rr) * BZ + b) * DIM + fcol] = acc[mt][nt][rr] + bv;
        }
    }
}

extern "C" void kernel_launch(void* const* d_in, const int* in_sizes, int n_in,
                              void* d_out, int out_size, void* d_ws, size_t ws_size,
                              hipStream_t stream)
{
    const float* x        = (const float*)d_in[0];
    const int*   lang_ids = (const int*)d_in[1];
    const float* W_base   = (const float*)d_in[2];
    const float* b_base   = (const float*)d_in[3];
    const float* W        = (const float*)d_in[4];
    const float* bias     = (const float*)d_in[5];
    const int*   dict_len = (const int*)d_in[6];
    float* out = (float*)d_out;

    char* ws = (char*)d_ws;
    u16*  Wt  = (u16*)ws;                                   // 2 MB
    u16*  Wbt = (u16*)(ws + (size_t)(2u << 20));            // 32 MB
    u16*  CT  = (u16*)(ws + (size_t)(34u << 20));           // 32 MB
    float* bb = (float*)(ws + (size_t)(66u << 20));         // 64 KB
    u16*  xb  = (u16*)(ws + (size_t)(67u << 20));           // 64 MB

    convert_x<<<dim3(SEQ, 1, 1), 256, 0, stream>>>(x, xb);
    transpose_cvt<<<dim3(32, 32, 17), dim3(32, 8, 1), 0, stream>>>(
        W, W_base, lang_ids, dict_len, Wt, Wbt);
    bb_kernel<<<dim3(4096, 1, 1), 256, 0, stream>>>(
        Wbt, b_base, bias, lang_ids, dict_len, bb);
    gemm1_kernel<<<dim3(1024, 1, 1), 256, 0, stream>>>(Wbt, Wt, CT);
    gemm2_kernel<<<dim3(2048, 1, 1), 256, 0, stream>>>(xb, CT, bb, out);
}